// Round 23
// baseline (323.900 us; speedup 1.0000x reference)
//
#include <hip/hip_runtime.h>
#include <hip/hip_bf16.h>
#include <stdint.h>

// Problem constants (B=2, T=2048, D=1024, F=4096, E=8)
#define N_TOK 4096      // B*T
#define D_DIM 1024
#define F_DIM 4096
#define E_NUM 8

typedef unsigned short u16;
typedef __attribute__((ext_vector_type(8))) short short8;   // 8 bf16 (4 VGPRs)
typedef __attribute__((ext_vector_type(4))) float f32x4;

__device__ __forceinline__ u16 f2bf(float f) {
  union { float f; uint32_t u; } v; v.f = f;
  uint32_t u = v.u;
  uint32_t r = (u + 0x7FFFu + ((u >> 16) & 1u)) >> 16;
  return (u16)r;
}

__device__ __forceinline__ void gld_lds16(const u16* g, u16* l) {
  // async global->LDS, 16B per lane; LDS dest = wave-uniform base + lane*16
  __builtin_amdgcn_global_load_lds(
      (const __attribute__((address_space(1))) uint32_t*)g,
      (__attribute__((address_space(3))) uint32_t*)l, 16, 0, 0);
}

// ==== fused prep: gate (blocks 0..1023) + W1/W2 transpose (1024..9215) ====
// Transpose blocks cover 64r x 128c (2x work/thread vs r22): 8 independent
// float4 loads in flight per thread (MLP-bound fix), 64B/lane coalesced store.
__global__ __launch_bounds__(256) void prep_kernel(
    const float* __restrict__ x, const float* __restrict__ Wg,
    const float* __restrict__ W1, const float* __restrict__ W2,
    u16* __restrict__ xb, int2* __restrict__ choice, float* __restrict__ sc2,
    u16* __restrict__ w1t, u16* __restrict__ w2t) {
  int bid = blockIdx.x;
  if (bid < 1024) {
    // ---- gate: 4 tokens per block (1 token/wave) + fused x->bf16 convert ----
    int n = bid * 4 + (threadIdx.x >> 6);
    int l = threadIdx.x & 63;
    const float* xr = x + (size_t)n * D_DIM;
    u16* xbr = xb + (size_t)n * D_DIM;
    float acc[E_NUM];
#pragma unroll
    for (int e = 0; e < E_NUM; ++e) acc[e] = 0.f;
    for (int d = l; d < D_DIM; d += 64) {
      float xv = xr[d];
      xbr[d] = f2bf(xv);
#pragma unroll
      for (int e = 0; e < E_NUM; ++e) acc[e] += xv * Wg[e * D_DIM + d];
    }
#pragma unroll
    for (int e = 0; e < E_NUM; ++e) {
      float v = acc[e];
#pragma unroll
      for (int off = 32; off > 0; off >>= 1) v += __shfl_xor(v, off);
      acc[e] = v;
    }
    if (l == 0) {
      int i0 = 0; float m0 = acc[0];
#pragma unroll
      for (int e = 1; e < E_NUM; ++e) if (acc[e] > m0) { m0 = acc[e]; i0 = e; }
      int i1 = -1; float m1 = -INFINITY;
#pragma unroll
      for (int e = 0; e < E_NUM; ++e) if (e != i0 && acc[e] > m1) { m1 = acc[e]; i1 = e; }
      float z = __expf(m1 - m0);
      float s0 = 1.f / (1.f + z);
      sc2[n * 2 + 0] = s0;
      sc2[n * 2 + 1] = 1.f - s0;
      choice[n] = make_int2(i0, i1);
    }
    return;
  }
  // ---- transpose+convert, 64r x 128c region, register-4x4 sub-blocks ----
  __shared__ u16 tile[128][72];   // 144B row stride (16B-aligned rows)
  const float* src; u16* dst; int R, C, bx, by, e;
  if (bid < 1024 + 4096) {
    int s = bid - 1024; bx = s & 31; by = (s >> 5) & 15; e = s >> 9;
    R = D_DIM; C = F_DIM;        // W1 [1024][4096] -> w1t [4096][1024]
    src = W1 + (size_t)e * R * C; dst = w1t + (size_t)e * R * C;
  } else {
    int s = bid - 1024 - 4096; bx = s & 7; by = (s >> 3) & 63; e = s >> 9;
    R = F_DIM; C = D_DIM;        // W2 [4096][1024] -> w2t [1024][4096]
    src = W2 + (size_t)e * R * C; dst = w2t + (size_t)e * R * C;
  }
  int r0 = by * 64, c0 = bx * 128;
  int tid = threadIdx.x;
  // load/transpose phase: thread (sc, sr) owns rows r0+sr*4..+3,
  // cols c0 + h*64 + sc*4..+3 for h = 0,1  (8 float4 loads, all independent)
  {
    int sc = tid & 15, sr = tid >> 4;   // sr in 0..15
    const float* base0 = &src[(size_t)(r0 + sr * 4) * C + c0 + sc * 4];
    float4 v[2][4];
#pragma unroll
    for (int h = 0; h < 2; ++h)
#pragma unroll
      for (int j = 0; j < 4; ++j)
        v[h][j] = *(const float4*)(base0 + (size_t)j * C + h * 64);
#pragma unroll
    for (int h = 0; h < 2; ++h) {
#pragma unroll
      for (int q = 0; q < 4; ++q) {   // q = col within 4x4 block
        ushort4 w;
        float* f0 = (float*)&v[h][0];
        w.x = f2bf(((const float*)&v[h][0])[q]);
        w.y = f2bf(((const float*)&v[h][1])[q]);
        w.z = f2bf(((const float*)&v[h][2])[q]);
        w.w = f2bf(((const float*)&v[h][3])[q]);
        *(ushort4*)&tile[h * 64 + sc * 4 + q][sr * 4] = w;
        (void)f0;
      }
    }
  }
  __syncthreads();
  // store phase: thread covers dst row (c0+c), 64B chunk rq (r-elems rq*32..+31)
  {
    int c = tid >> 1, rq = tid & 1;
    u16* dp = &dst[(size_t)(c0 + c) * R + r0 + rq * 32];
    const u16* tp = &tile[c][rq * 32];
    uint4 a0 = *(const uint4*)(tp + 0);
    uint4 a1 = *(const uint4*)(tp + 8);
    uint4 a2 = *(const uint4*)(tp + 16);
    uint4 a3 = *(const uint4*)(tp + 24);
    *(uint4*)(dp + 0)  = a0;
    *(uint4*)(dp + 8)  = a1;
    *(uint4*)(dp + 16) = a2;
    *(uint4*)(dp + 24) = a3;
  }
}

// ---------------- route: deterministic ballot-prefix compaction ----------------
__global__ void route_kernel(const int2* __restrict__ choice, int* __restrict__ cnt,
                             int* __restrict__ tok_list) {
  int e = blockIdx.x;
  int l = threadIdx.x;  // 64
  unsigned long long below = (l == 0) ? 0ull : ((~0ull) >> (64 - l));
  int c = 0;
  for (int it = 0; it < N_TOK / 64; ++it) {
    int n = it * 64 + l;
    int2 ch = choice[n];
    unsigned long long b0 = __ballot(ch.x == e);
    if (ch.x == e) tok_list[e * N_TOK + c + __popcll(b0 & below)] = 2 * n;
    c += __popcll(b0);
    unsigned long long b1 = __ballot(ch.y == e);
    if (ch.y == e) tok_list[e * N_TOK + c + __popcll(b1 & below)] = 2 * n + 1;
    c += __popcll(b1);
  }
  if (l == 0) cnt[e] = c;
}

__global__ void prefix_kernel(const int* __restrict__ cnt, int* __restrict__ base) {
  if (threadIdx.x == 0) {
    int s = 0;
    for (int e = 0; e < E_NUM; ++e) { base[e] = s; s += cnt[e]; }
  }
}

// ---------------- up GEMM: act[be+i][f] = silu( x[tok_i] @ W1[e] ) ----------------
// r18 config (verified): 128x128, BK=32, 8 waves (2M x 4N, acc[4][2]), dbuf,
// counted vmcnt(2), raw barriers. Grid 8192 -> 4 blocks/CU. XCD-chunked q=1024.
__global__ __launch_bounds__(512) void up_gemm(
    const u16* __restrict__ xb, const u16* __restrict__ w1t,
    const int* __restrict__ cnt, const int* __restrict__ base,
    const int* __restrict__ tok_list, u16* __restrict__ act) {
  __shared__ u16 As[2][128 * 32];
  __shared__ u16 Bs[2][128 * 32];

  const int bid = blockIdx.x;
  const int orig = (bid & 7) * 1024 + (bid >> 3);   // bijective: 8192 % 8 == 0
  const int bx = orig & 31, by = (orig >> 5) & 31, e = orig >> 10;

  const int ce = cnt[e];
  const int row0 = by * 128;
  if (row0 >= ce) return;
  const int col0 = bx * 128;
  const int be = base[e];

  const int tid = threadIdx.x;
  const int wave = tid >> 6, lane = tid & 63;
  const int wm = wave >> 2, wn = wave & 3;          // 2M x 4N
  const int lr = lane & 15, kq = lane >> 4;

  const int rsA = wave * 16 + (lane >> 2);          // one 16-row segment per wave
  const int kb = (((lane & 3) ^ ((lane >> 3) & 3)) * 8);  // swizzled write k-offset
  const int kq8 = ((kq ^ ((lr >> 1) & 3)) * 8);           // swizzled read k-offset

  int ga = row0 + rsA;
  int e0 = (ga < ce) ? (tok_list[e * N_TOK + ga] & (2 * N_TOK - 1)) : 0;
  const u16* srcA = xb + (e0 >> 1) * D_DIM + kb;
  const u16* srcB = w1t + (size_t)(e * F_DIM + col0 + rsA) * D_DIM + kb;

  f32x4 acc[4][2];
#pragma unroll
  for (int m = 0; m < 4; ++m)
#pragma unroll
    for (int n = 0; n < 2; ++n) acc[m][n] = (f32x4){0.f, 0.f, 0.f, 0.f};

#define USTAGE(k0, b)                              \
  do {                                             \
    gld_lds16(srcA + (k0), &As[b][wave * 512]);    \
    gld_lds16(srcB + (k0), &Bs[b][wave * 512]);    \
  } while (0)

#define UCOMPUTE(b)                                                           \
  do {                                                                        \
    short8 a[4], bb[2];                                                       \
    _Pragma("unroll") for (int m = 0; m < 4; ++m)                             \
        a[m] = *(const short8*)&As[b][(wm * 64 + m * 16 + lr) * 32 + kq8];    \
    _Pragma("unroll") for (int n = 0; n < 2; ++n)                             \
        bb[n] = *(const short8*)&Bs[b][(wn * 32 + n * 16 + lr) * 32 + kq8];   \
    _Pragma("unroll") for (int m = 0; m < 4; ++m)                             \
        _Pragma("unroll") for (int n = 0; n < 2; ++n)                         \
            acc[m][n] = __builtin_amdgcn_mfma_f32_16x16x32_bf16(a[m], bb[n], acc[m][n], 0, 0, 0); \
  } while (0)

  const int NT = D_DIM / 32;   // 32 K-steps
  USTAGE(0, 0);
  USTAGE(32, 1);
  asm volatile("s_waitcnt vmcnt(2)" ::: "memory");
  __builtin_amdgcn_s_barrier();
  __builtin_amdgcn_sched_barrier(0);
  int cur = 0;
  for (int t = 0; t < NT; ++t) {
    UCOMPUTE(cur);
    __builtin_amdgcn_sched_barrier(0);
    __builtin_amdgcn_s_barrier();
    __builtin_amdgcn_sched_barrier(0);
    if (t + 2 < NT) {
      USTAGE((t + 2) * 32, cur);
      asm volatile("s_waitcnt vmcnt(2)" ::: "memory");
    } else {
      asm volatile("s_waitcnt vmcnt(0)" ::: "memory");
    }
    __builtin_amdgcn_s_barrier();
    __builtin_amdgcn_sched_barrier(0);
    cur ^= 1;
  }
#undef USTAGE
#undef UCOMPUTE

  // epilogue: silu (native exp) -> bf16 act
#pragma unroll
  for (int m = 0; m < 4; ++m) {
#pragma unroll
    for (int rg = 0; rg < 4; ++rg) {
      int row = wm * 64 + m * 16 + kq * 4 + rg;
      int i = row0 + row;
      if (i < ce) {
        u16* dst = act + (size_t)(be + i) * F_DIM + col0 + wn * 32;
#pragma unroll
        for (int n = 0; n < 2; ++n) {
          float v = acc[m][n][rg];
          float s = v / (1.f + __expf(-v));
          dst[n * 16 + lr] = f2bf(s);
        }
      }
    }
  }
}

// ---------------- down GEMM: out[tok] += score * ( act_row @ W2[e] ) ----------------
// r13 verified best (121 us): 8 waves, 128x128, BK=32, dbuf, counted vmcnt(2),
// raw barriers. Grid 2048 (8x * 32y * 8e), XCD-chunked q=256.
__global__ __launch_bounds__(512) void down_gemm(
    const u16* __restrict__ act, const u16* __restrict__ w2t,
    const int* __restrict__ cnt, const int* __restrict__ base,
    const int* __restrict__ tok_list, const float* __restrict__ sc2,
    float* __restrict__ out) {
  __shared__ u16 As[2][128 * 32];
  __shared__ u16 Bs[2][128 * 32];
  __shared__ int toks[128];

  const int bid = blockIdx.x;
  const int orig = (bid & 7) * 256 + (bid >> 3);    // bijective: 2048 % 8 == 0
  const int bx = orig & 7, by = (orig >> 3) & 31, e = orig >> 8;

  const int ce = cnt[e];
  const int row0 = by * 128;
  if (row0 >= ce) return;
  const int col0 = bx * 128;
  const int be = base[e];

  const int tid = threadIdx.x;
  const int wave = tid >> 6, lane = tid & 63;
  const int wm = wave >> 2, wn = wave & 3;          // 2M x 4N
  const int lr = lane & 15, kq = lane >> 4;

  if (tid < 128) {
    int i = row0 + tid;
    toks[tid] = (i < ce) ? tok_list[e * N_TOK + i] : -1;
  }
  __syncthreads();   // toks visible before raw-barrier loop

  const int rsA = wave * 16 + (lane >> 2);          // one 16-row segment per wave
  const int kb = (((lane & 3) ^ ((lane >> 3) & 3)) * 8);  // swizzled write k-offset
  const int kq8 = ((kq ^ ((lr >> 1) & 3)) * 8);           // swizzled read k-offset

  int ra = min(be + row0 + rsA, 2 * N_TOK - 1);     // clamp inside act buffer
  const u16* srcA = act + (size_t)ra * F_DIM + kb;
  const u16* srcB = w2t + (size_t)(e * D_DIM + col0 + rsA) * F_DIM + kb;

  f32x4 acc[4][2];
#pragma unroll
  for (int m = 0; m < 4; ++m)
#pragma unroll
    for (int n = 0; n < 2; ++n) acc[m][n] = (f32x4){0.f, 0.f, 0.f, 0.f};

#define DSTAGE(k0, b)                              \
  do {                                             \
    gld_lds16(srcA + (k0), &As[b][wave * 512]);    \
    gld_lds16(srcB + (k0), &Bs[b][wave * 512]);    \
  } while (0)

#define DCOMPUTE(b)                                                           \
  do {                                                                        \
    short8 a[4], bb[2];                                                       \
    _Pragma("unroll") for (int m = 0; m < 4; ++m)                             \
        a[m] = *(const short8*)&As[b][(wm * 64 + m * 16 + lr) * 32 + kq8];    \
    _Pragma("unroll") for (int n = 0; n < 2; ++n)                             \
        bb[n] = *(const short8*)&Bs[b][(wn * 32 + n * 16 + lr) * 32 + kq8];   \
    _Pragma("unroll") for (int m = 0; m < 4; ++m)                             \
        _Pragma("unroll") for (int n = 0; n < 2; ++n)                         \
            acc[m][n] = __builtin_amdgcn_mfma_f32_16x16x32_bf16(a[m], bb[n], acc[m][n], 0, 0, 0); \
  } while (0)

  const int NT = F_DIM / 32;   // 128 K-steps
  DSTAGE(0, 0);
  DSTAGE(32, 1);
  asm volatile("s_waitcnt vmcnt(2)" ::: "memory");   // buf0 landed (per-wave)
  __builtin_amdgcn_s_barrier();
  __builtin_amdgcn_sched_barrier(0);
  int cur = 0;
  for (int t = 0; t < NT; ++t) {
    DCOMPUTE(cur);
    __builtin_amdgcn_sched_barrier(0);
    __builtin_amdgcn_s_barrier();   // all readers done with buf cur
    __builtin_amdgcn_sched_barrier(0);
    if (t + 2 < NT) {
      DSTAGE((t + 2) * 32, cur);
      asm volatile("s_waitcnt vmcnt(2)" ::: "memory");  // buf cur^1 landed
    } else {
      asm volatile("s_waitcnt vmcnt(0)" ::: "memory");
    }
    __builtin_amdgcn_s_barrier();   // next buffer ready for all waves
    __builtin_amdgcn_sched_barrier(0);
    cur ^= 1;
  }
#undef DSTAGE
#undef DCOMPUTE

  // epilogue: score-scaled atomic scatter (fp32 adds, commutative; 2 adds/elem)
#pragma unroll
  for (int m = 0; m < 4; ++m) {
#pragma unroll
    for (int rg = 0; rg < 4; ++rg) {
      int row = wm * 64 + m * 16 + kq * 4 + rg;
      int ent = toks[row];
      if (ent >= 0) {
        int tokn = ent >> 1;
        float sc = sc2[tokn * 2 + (ent & 1)];
        float* dst = out + (size_t)tokn * D_DIM + col0 + wn * 32;
#pragma unroll
        for (int n = 0; n < 2; ++n)
          atomicAdd(&dst[n * 16 + lr], acc[m][n][rg] * sc);
      }
    }
  }
}

extern "C" void kernel_launch(void* const* d_in, const int* in_sizes, int n_in,
                              void* d_out, int out_size, void* d_ws, size_t ws_size,
                              hipStream_t stream) {
  const float* x  = (const float*)d_in[0];
  const float* Wg = (const float*)d_in[1];
  const float* W1 = (const float*)d_in[2];
  const float* W2 = (const float*)d_in[3];
  float* out = (float*)d_out;

  // workspace layout (~200.3 MiB total)
  char* ws = (char*)d_ws;
  size_t off = 0;
  u16* xb  = (u16*)(ws + off); off += (size_t)N_TOK * D_DIM * 2;          // 8 MiB
  u16* w1t = (u16*)(ws + off); off += (size_t)E_NUM * F_DIM * D_DIM * 2;  // 64 MiB
  u16* w2t = (u16*)(ws + off); off += (size_t)E_NUM * D_DIM * F_DIM * 2;  // 64 MiB
  u16* act = (u16*)(ws + off); off += (size_t)2 * N_TOK * F_DIM * 2;      // 64 MiB
  int* tok_list = (int*)(ws + off); off += (size_t)E_NUM * N_TOK * 4;     // 128 KiB
  float* sc2 = (float*)(ws + off); off += (size_t)N_TOK * 2 * 4;          // 32 KiB
  int2* choice = (int2*)(ws + off); off += (size_t)N_TOK * 8;             // 32 KiB
  int* cnt  = (int*)(ws + off); off += 128;
  int* base = (int*)(ws + off); off += 128;

  hipMemsetAsync(d_out, 0, (size_t)out_size * 4, stream);

  prep_kernel<<<dim3(1024 + 8192), 256, 0, stream>>>(x, Wg, W1, W2, xb, choice,
                                                     sc2, w1t, w2t);
  route_kernel<<<E_NUM, 64, 0, stream>>>(choice, cnt, tok_list);
  prefix_kernel<<<1, 1, 0, stream>>>(cnt, base);

  up_gemm<<<dim3(8192), 512, 0, stream>>>(xb, w1t, cnt, base, tok_list, act);
  down_gemm<<<dim3(2048), 512, 0, stream>>>(act, w2t, cnt, base, tok_list, sc2, out);
}

// Round 24
// 314.509 us; speedup vs baseline: 1.0299x; 1.0299x over previous
//
#include <hip/hip_runtime.h>
#include <hip/hip_bf16.h>
#include <stdint.h>

// Problem constants (B=2, T=2048, D=1024, F=4096, E=8)
#define N_TOK 4096      // B*T
#define D_DIM 1024
#define F_DIM 4096
#define E_NUM 8

typedef unsigned short u16;
typedef __attribute__((ext_vector_type(8))) short short8;   // 8 bf16 (4 VGPRs)
typedef __attribute__((ext_vector_type(4))) float f32x4;

__device__ __forceinline__ u16 f2bf(float f) {
  union { float f; uint32_t u; } v; v.f = f;
  uint32_t u = v.u;
  uint32_t r = (u + 0x7FFFu + ((u >> 16) & 1u)) >> 16;
  return (u16)r;
}

__device__ __forceinline__ void gld_lds16(const u16* g, u16* l) {
  // async global->LDS, 16B per lane; LDS dest = wave-uniform base + lane*16
  __builtin_amdgcn_global_load_lds(
      (const __attribute__((address_space(1))) uint32_t*)g,
      (__attribute__((address_space(3))) uint32_t*)l, 16, 0, 0);
}

// ==== prep: gate (blocks 0..1023) + W1 transpose (1024..9215) ====
// W2's transpose moved into the up_gemm dispatch (only down consumes w2t).
__global__ __launch_bounds__(256) void prep_kernel(
    const float* __restrict__ x, const float* __restrict__ Wg,
    const float* __restrict__ W1,
    u16* __restrict__ xb, int2* __restrict__ choice, float* __restrict__ sc2,
    u16* __restrict__ w1t) {
  int bid = blockIdx.x;
  if (bid < 1024) {
    // ---- gate: 4 tokens per block (1 token/wave) + fused x->bf16 convert ----
    int n = bid * 4 + (threadIdx.x >> 6);
    int l = threadIdx.x & 63;
    const float* xr = x + (size_t)n * D_DIM;
    u16* xbr = xb + (size_t)n * D_DIM;
    float acc[E_NUM];
#pragma unroll
    for (int e = 0; e < E_NUM; ++e) acc[e] = 0.f;
    for (int d = l; d < D_DIM; d += 64) {
      float xv = xr[d];
      xbr[d] = f2bf(xv);
#pragma unroll
      for (int e = 0; e < E_NUM; ++e) acc[e] += xv * Wg[e * D_DIM + d];
    }
#pragma unroll
    for (int e = 0; e < E_NUM; ++e) {
      float v = acc[e];
#pragma unroll
      for (int off = 32; off > 0; off >>= 1) v += __shfl_xor(v, off);
      acc[e] = v;
    }
    if (l == 0) {
      int i0 = 0; float m0 = acc[0];
#pragma unroll
      for (int e = 1; e < E_NUM; ++e) if (acc[e] > m0) { m0 = acc[e]; i0 = e; }
      int i1 = -1; float m1 = -INFINITY;
#pragma unroll
      for (int e = 0; e < E_NUM; ++e) if (e != i0 && acc[e] > m1) { m1 = acc[e]; i1 = e; }
      float z = __expf(m1 - m0);
      float s0 = 1.f / (1.f + z);
      sc2[n * 2 + 0] = s0;
      sc2[n * 2 + 1] = 1.f - s0;
      choice[n] = make_int2(i0, i1);
    }
    return;
  }
  // ---- W1 transpose+convert: [E][1024][4096] f32 -> [E][4096][1024] bf16 ----
  // r21-proven 64x64 tile code.
  __shared__ u16 tile[64][72];   // pad 72: 144B row stride (16B-aligned)
  int s = bid - 1024;
  int bx = s & 63, by = (s >> 6) & 15, e = s >> 10;
  const int R = D_DIM, C = F_DIM;
  const float* src = W1 + (size_t)e * R * C;
  u16* dst = w1t + (size_t)e * R * C;
  int r0 = by * 64, c0 = bx * 64;
  int tid = threadIdx.x;
  int lr = tid & 15;    // 16 lanes cover 64 elems
  int rr = tid >> 4;    // 16 rows / pass
#pragma unroll
  for (int p = 0; p < 4; ++p) {
    int r = rr + p * 16;
    float4 v = *(const float4*)&src[(size_t)(r0 + r) * C + c0 + lr * 4];
    tile[lr * 4 + 0][r] = f2bf(v.x);
    tile[lr * 4 + 1][r] = f2bf(v.y);
    tile[lr * 4 + 2][r] = f2bf(v.z);
    tile[lr * 4 + 3][r] = f2bf(v.w);
  }
  __syncthreads();
#pragma unroll
  for (int p = 0; p < 4; ++p) {
    int c = rr + p * 16;
    ushort4 o = *(const ushort4*)&tile[c][lr * 4];
    *(ushort4*)&dst[(size_t)(c0 + c) * R + r0 + lr * 4] = o;
  }
}

// ---------------- route: deterministic ballot-prefix compaction ----------------
__global__ void route_kernel(const int2* __restrict__ choice, int* __restrict__ cnt,
                             int* __restrict__ tok_list) {
  int e = blockIdx.x;
  int l = threadIdx.x;  // 64
  unsigned long long below = (l == 0) ? 0ull : ((~0ull) >> (64 - l));
  int c = 0;
  for (int it = 0; it < N_TOK / 64; ++it) {
    int n = it * 64 + l;
    int2 ch = choice[n];
    unsigned long long b0 = __ballot(ch.x == e);
    if (ch.x == e) tok_list[e * N_TOK + c + __popcll(b0 & below)] = 2 * n;
    c += __popcll(b0);
    unsigned long long b1 = __ballot(ch.y == e);
    if (ch.y == e) tok_list[e * N_TOK + c + __popcll(b1 & below)] = 2 * n + 1;
    c += __popcll(b1);
  }
  if (l == 0) cnt[e] = c;
}

__global__ void prefix_kernel(const int* __restrict__ cnt, int* __restrict__ base) {
  if (threadIdx.x == 0) {
    int s = 0;
    for (int e = 0; e < E_NUM; ++e) { base[e] = s; s += cnt[e]; }
  }
}

// ==== up GEMM dispatch: W2 transpose (blocks 0..4095) + up GEMM (4096..12287) ====
// W2T overlaps with up's MFMA work (complementary pipes); w2t is only read by
// down_gemm, which launches after this dispatch completes. LDS unioned.
__global__ __launch_bounds__(512) void up_gemm(
    const u16* __restrict__ xb, const u16* __restrict__ w1t,
    const float* __restrict__ W2, u16* __restrict__ w2t,
    const int* __restrict__ cnt, const int* __restrict__ base,
    const int* __restrict__ tok_list, u16* __restrict__ act) {
  __shared__ u16 smem[16384];   // 32 KB union: GEMM As/Bs or transpose tile

  const int bid = blockIdx.x;
  if (bid < 4096) {
    // ---- W2 transpose+convert: [E][4096][1024] f32 -> [E][1024][4096] bf16 ----
    // 64r x 128c region, 512 threads, register-4x4 (r23-proven pattern).
    u16 (*tile)[72] = (u16(*)[72])smem;   // [128][72], 18.4 KB
    int s = bid;
    int bx = s & 7, by = (s >> 3) & 63, e = s >> 9;
    const int R = F_DIM, C = D_DIM;
    const float* src = W2 + (size_t)e * R * C;
    u16* dst = w2t + (size_t)e * R * C;   // dst rows length R
    int r0 = by * 64, c0 = bx * 128;
    int tid = threadIdx.x;
    {
      int sc = tid & 31, sr = tid >> 5;   // 32 col-groups x 16 row-groups
      const float* b0p = &src[(size_t)(r0 + sr * 4) * C + c0 + sc * 4];
      float4 v0 = *(const float4*)(b0p + 0 * C);
      float4 v1 = *(const float4*)(b0p + 1 * C);
      float4 v2 = *(const float4*)(b0p + 2 * C);
      float4 v3 = *(const float4*)(b0p + 3 * C);
      ushort4 w;
      w.x = f2bf(v0.x); w.y = f2bf(v1.x); w.z = f2bf(v2.x); w.w = f2bf(v3.x);
      *(ushort4*)&tile[sc * 4 + 0][sr * 4] = w;
      w.x = f2bf(v0.y); w.y = f2bf(v1.y); w.z = f2bf(v2.y); w.w = f2bf(v3.y);
      *(ushort4*)&tile[sc * 4 + 1][sr * 4] = w;
      w.x = f2bf(v0.z); w.y = f2bf(v1.z); w.z = f2bf(v2.z); w.w = f2bf(v3.z);
      *(ushort4*)&tile[sc * 4 + 2][sr * 4] = w;
      w.x = f2bf(v0.w); w.y = f2bf(v1.w); w.z = f2bf(v2.w); w.w = f2bf(v3.w);
      *(ushort4*)&tile[sc * 4 + 3][sr * 4] = w;
    }
    __syncthreads();
    {
      int c = tid >> 2, rq = tid & 3;   // 128 dst rows x 4 chunks of 16 elems
      u16* dp = &dst[(size_t)(c0 + c) * R + r0 + rq * 16];
      const u16* tp = &tile[c][rq * 16];
      uint4 a0 = *(const uint4*)(tp + 0);
      uint4 a1 = *(const uint4*)(tp + 8);
      *(uint4*)(dp + 0) = a0;
      *(uint4*)(dp + 8) = a1;
    }
    return;
  }

  // ---- up GEMM: r18 config (verified): 128x128, BK=32, 8 waves, dbuf,
  // counted vmcnt(2), raw barriers, XCD-chunked q=1024 on ubid.
  u16 (*As)[4096] = (u16(*)[4096])smem;            // As[2]
  u16 (*Bs)[4096] = (u16(*)[4096])(smem + 8192);   // Bs[2]

  const int ubid = bid - 4096;
  const int orig = (ubid & 7) * 1024 + (ubid >> 3);   // bijective: 8192 % 8 == 0
  const int bx = orig & 31, by = (orig >> 5) & 31, e = orig >> 10;

  const int ce = cnt[e];
  const int row0 = by * 128;
  if (row0 >= ce) return;
  const int col0 = bx * 128;
  const int be = base[e];

  const int tid = threadIdx.x;
  const int wave = tid >> 6, lane = tid & 63;
  const int wm = wave >> 2, wn = wave & 3;          // 2M x 4N
  const int lr = lane & 15, kq = lane >> 4;

  const int rsA = wave * 16 + (lane >> 2);          // one 16-row segment per wave
  const int kb = (((lane & 3) ^ ((lane >> 3) & 3)) * 8);  // swizzled write k-offset
  const int kq8 = ((kq ^ ((lr >> 1) & 3)) * 8);           // swizzled read k-offset

  int ga = row0 + rsA;
  int e0 = (ga < ce) ? (tok_list[e * N_TOK + ga] & (2 * N_TOK - 1)) : 0;
  const u16* srcA = xb + (e0 >> 1) * D_DIM + kb;
  const u16* srcB = w1t + (size_t)(e * F_DIM + col0 + rsA) * D_DIM + kb;

  f32x4 acc[4][2];
#pragma unroll
  for (int m = 0; m < 4; ++m)
#pragma unroll
    for (int n = 0; n < 2; ++n) acc[m][n] = (f32x4){0.f, 0.f, 0.f, 0.f};

#define USTAGE(k0, b)                              \
  do {                                             \
    gld_lds16(srcA + (k0), &As[b][wave * 512]);    \
    gld_lds16(srcB + (k0), &Bs[b][wave * 512]);    \
  } while (0)

#define UCOMPUTE(b)                                                           \
  do {                                                                        \
    short8 a[4], bb[2];                                                       \
    _Pragma("unroll") for (int m = 0; m < 4; ++m)                             \
        a[m] = *(const short8*)&As[b][(wm * 64 + m * 16 + lr) * 32 + kq8];    \
    _Pragma("unroll") for (int n = 0; n < 2; ++n)                             \
        bb[n] = *(const short8*)&Bs[b][(wn * 32 + n * 16 + lr) * 32 + kq8];   \
    _Pragma("unroll") for (int m = 0; m < 4; ++m)                             \
        _Pragma("unroll") for (int n = 0; n < 2; ++n)                         \
            acc[m][n] = __builtin_amdgcn_mfma_f32_16x16x32_bf16(a[m], bb[n], acc[m][n], 0, 0, 0); \
  } while (0)

  const int NT = D_DIM / 32;   // 32 K-steps
  USTAGE(0, 0);
  USTAGE(32, 1);
  asm volatile("s_waitcnt vmcnt(2)" ::: "memory");
  __builtin_amdgcn_s_barrier();
  __builtin_amdgcn_sched_barrier(0);
  int cur = 0;
  for (int t = 0; t < NT; ++t) {
    UCOMPUTE(cur);
    __builtin_amdgcn_sched_barrier(0);
    __builtin_amdgcn_s_barrier();
    __builtin_amdgcn_sched_barrier(0);
    if (t + 2 < NT) {
      USTAGE((t + 2) * 32, cur);
      asm volatile("s_waitcnt vmcnt(2)" ::: "memory");
    } else {
      asm volatile("s_waitcnt vmcnt(0)" ::: "memory");
    }
    __builtin_amdgcn_s_barrier();
    __builtin_amdgcn_sched_barrier(0);
    cur ^= 1;
  }
#undef USTAGE
#undef UCOMPUTE

  // epilogue: silu (native exp) -> bf16 act
#pragma unroll
  for (int m = 0; m < 4; ++m) {
#pragma unroll
    for (int rg = 0; rg < 4; ++rg) {
      int row = wm * 64 + m * 16 + kq * 4 + rg;
      int i = row0 + row;
      if (i < ce) {
        u16* dst = act + (size_t)(be + i) * F_DIM + col0 + wn * 32;
#pragma unroll
        for (int n = 0; n < 2; ++n) {
          float v = acc[m][n][rg];
          float s = v / (1.f + __expf(-v));
          dst[n * 16 + lr] = f2bf(s);
        }
      }
    }
  }
}

// ---------------- down GEMM: out[tok] += score * ( act_row @ W2[e] ) ----------------
// r13 verified best (121 us): 8 waves, 128x128, BK=32, dbuf, counted vmcnt(2),
// raw barriers. Grid 2048 (8x * 32y * 8e), XCD-chunked q=256.
__global__ __launch_bounds__(512) void down_gemm(
    const u16* __restrict__ act, const u16* __restrict__ w2t,
    const int* __restrict__ cnt, const int* __restrict__ base,
    const int* __restrict__ tok_list, const float* __restrict__ sc2,
    float* __restrict__ out) {
  __shared__ u16 As[2][128 * 32];
  __shared__ u16 Bs[2][128 * 32];
  __shared__ int toks[128];

  const int bid = blockIdx.x;
  const int orig = (bid & 7) * 256 + (bid >> 3);    // bijective: 2048 % 8 == 0
  const int bx = orig & 7, by = (orig >> 3) & 31, e = orig >> 8;

  const int ce = cnt[e];
  const int row0 = by * 128;
  if (row0 >= ce) return;
  const int col0 = bx * 128;
  const int be = base[e];

  const int tid = threadIdx.x;
  const int wave = tid >> 6, lane = tid & 63;
  const int wm = wave >> 2, wn = wave & 3;          // 2M x 4N
  const int lr = lane & 15, kq = lane >> 4;

  if (tid < 128) {
    int i = row0 + tid;
    toks[tid] = (i < ce) ? tok_list[e * N_TOK + i] : -1;
  }
  __syncthreads();   // toks visible before raw-barrier loop

  const int rsA = wave * 16 + (lane >> 2);          // one 16-row segment per wave
  const int kb = (((lane & 3) ^ ((lane >> 3) & 3)) * 8);  // swizzled write k-offset
  const int kq8 = ((kq ^ ((lr >> 1) & 3)) * 8);           // swizzled read k-offset

  int ra = min(be + row0 + rsA, 2 * N_TOK - 1);     // clamp inside act buffer
  const u16* srcA = act + (size_t)ra * F_DIM + kb;
  const u16* srcB = w2t + (size_t)(e * D_DIM + col0 + rsA) * F_DIM + kb;

  f32x4 acc[4][2];
#pragma unroll
  for (int m = 0; m < 4; ++m)
#pragma unroll
    for (int n = 0; n < 2; ++n) acc[m][n] = (f32x4){0.f, 0.f, 0.f, 0.f};

#define DSTAGE(k0, b)                              \
  do {                                             \
    gld_lds16(srcA + (k0), &As[b][wave * 512]);    \
    gld_lds16(srcB + (k0), &Bs[b][wave * 512]);    \
  } while (0)

#define DCOMPUTE(b)                                                           \
  do {                                                                        \
    short8 a[4], bb[2];                                                       \
    _Pragma("unroll") for (int m = 0; m < 4; ++m)                             \
        a[m] = *(const short8*)&As[b][(wm * 64 + m * 16 + lr) * 32 + kq8];    \
    _Pragma("unroll") for (int n = 0; n < 2; ++n)                             \
        bb[n] = *(const short8*)&Bs[b][(wn * 32 + n * 16 + lr) * 32 + kq8];   \
    _Pragma("unroll") for (int m = 0; m < 4; ++m)                             \
        _Pragma("unroll") for (int n = 0; n < 2; ++n)                         \
            acc[m][n] = __builtin_amdgcn_mfma_f32_16x16x32_bf16(a[m], bb[n], acc[m][n], 0, 0, 0); \
  } while (0)

  const int NT = F_DIM / 32;   // 128 K-steps
  DSTAGE(0, 0);
  DSTAGE(32, 1);
  asm volatile("s_waitcnt vmcnt(2)" ::: "memory");   // buf0 landed (per-wave)
  __builtin_amdgcn_s_barrier();
  __builtin_amdgcn_sched_barrier(0);
  int cur = 0;
  for (int t = 0; t < NT; ++t) {
    DCOMPUTE(cur);
    __builtin_amdgcn_sched_barrier(0);
    __builtin_amdgcn_s_barrier();   // all readers done with buf cur
    __builtin_amdgcn_sched_barrier(0);
    if (t + 2 < NT) {
      DSTAGE((t + 2) * 32, cur);
      asm volatile("s_waitcnt vmcnt(2)" ::: "memory");  // buf cur^1 landed
    } else {
      asm volatile("s_waitcnt vmcnt(0)" ::: "memory");
    }
    __builtin_amdgcn_s_barrier();   // next buffer ready for all waves
    __builtin_amdgcn_sched_barrier(0);
    cur ^= 1;
  }
#undef DSTAGE
#undef DCOMPUTE

  // epilogue: score-scaled atomic scatter (fp32 adds, commutative; 2 adds/elem)
#pragma unroll
  for (int m = 0; m < 4; ++m) {
#pragma unroll
    for (int rg = 0; rg < 4; ++rg) {
      int row = wm * 64 + m * 16 + kq * 4 + rg;
      int ent = toks[row];
      if (ent >= 0) {
        int tokn = ent >> 1;
        float sc = sc2[tokn * 2 + (ent & 1)];
        float* dst = out + (size_t)tokn * D_DIM + col0 + wn * 32;
#pragma unroll
        for (int n = 0; n < 2; ++n)
          atomicAdd(&dst[n * 16 + lr], acc[m][n][rg] * sc);
      }
    }
  }
}

extern "C" void kernel_launch(void* const* d_in, const int* in_sizes, int n_in,
                              void* d_out, int out_size, void* d_ws, size_t ws_size,
                              hipStream_t stream) {
  const float* x  = (const float*)d_in[0];
  const float* Wg = (const float*)d_in[1];
  const float* W1 = (const float*)d_in[2];
  const float* W2 = (const float*)d_in[3];
  float* out = (float*)d_out;

  // workspace layout (~200.3 MiB total)
  char* ws = (char*)d_ws;
  size_t off = 0;
  u16* xb  = (u16*)(ws + off); off += (size_t)N_TOK * D_DIM * 2;          // 8 MiB
  u16* w1t = (u16*)(ws + off); off += (size_t)E_NUM * F_DIM * D_DIM * 2;  // 64 MiB
  u16* w2t = (u16*)(ws + off); off += (size_t)E_NUM * D_DIM * F_DIM * 2;  // 64 MiB
  u16* act = (u16*)(ws + off); off += (size_t)2 * N_TOK * F_DIM * 2;      // 64 MiB
  int* tok_list = (int*)(ws + off); off += (size_t)E_NUM * N_TOK * 4;     // 128 KiB
  float* sc2 = (float*)(ws + off); off += (size_t)N_TOK * 2 * 4;          // 32 KiB
  int2* choice = (int2*)(ws + off); off += (size_t)N_TOK * 8;             // 32 KiB
  int* cnt  = (int*)(ws + off); off += 128;
  int* base = (int*)(ws + off); off += 128;

  hipMemsetAsync(d_out, 0, (size_t)out_size * 4, stream);

  prep_kernel<<<dim3(1024 + 8192), 256, 0, stream>>>(x, Wg, W1, xb, choice,
                                                     sc2, w1t);
  route_kernel<<<E_NUM, 64, 0, stream>>>(choice, cnt, tok_list);
  prefix_kernel<<<1, 1, 0, stream>>>(cnt, base);

  up_gemm<<<dim3(4096 + 8192), 512, 0, stream>>>(xb, w1t, W2, w2t, cnt, base,
                                                 tok_list, act);
  down_gemm<<<dim3(2048), 512, 0, stream>>>(act, w2t, cnt, base, tok_list, sc2, out);
}